// Round 2
// baseline (3446.884 us; speedup 1.0000x reference)
//
#include <hip/hip_runtime.h>
#include <hip/hip_bf16.h>

// Problem: B=2, S=2048, D=1024, H=16, HD=64, RANK=8, ALPHA=8
// Input dtype is resolved AT RUNTIME by a sniffer kernel (fp32 vs bf16),
// because the harness's actual conversion policy is ambiguous. All
// intermediates fp32 in d_ws.

#define BB    2
#define SS    2048
#define DD    1024
#define HH    16
#define HDIM  64
#define RANK  8
#define MROWS (BB * SS)   // 4096
#define N3    (3 * DD)    // 3072

typedef __hip_bfloat16 bf16;

template<bool BF>
__device__ __forceinline__ float ld(const void* p, int i) {
    if constexpr (BF) return __bfloat162float(((const bf16*)p)[i]);
    else              return ((const float*)p)[i];
}

// ------------------------------------------------------------- dtype sniffer
// Examine even-indexed 16-bit halves of x. True bf16 N(0,1): exponent field
// in [110,144] for ~100% of samples. fp32 low-mantissa halves: uniform bits,
// ~14% in range. flag = 1 (bf16) iff >3000 of 4096 plausible.
__global__ __launch_bounds__(256) void sniff_kernel(const void* x, int* flag) {
    __shared__ int cnt;
    if (threadIdx.x == 0) cnt = 0;
    __syncthreads();
    const unsigned short* u = (const unsigned short*)x;
    int good = 0;
    for (int i = threadIdx.x; i < 4096; i += 256) {
        unsigned short bits = u[2 * i];
        int e = (bits >> 7) & 0xFF;
        if (e >= 110 && e <= 144) good++;
    }
    atomicAdd(&cnt, good);
    __syncthreads();
    if (threadIdx.x == 0) *flag = (cnt > 3000) ? 1 : 0;
}

// ---------------------------------------------------------------- xa = x @ A
template<bool BF>
__device__ void xa_body(const void* x, const void* A, float* xa) {
    int m = blockIdx.x;
    int l = threadIdx.x;
    int r = l & 7, k0 = l >> 3;
    float acc = 0.f;
    for (int k = k0; k < DD; k += 8)
        acc += ld<BF>(x, m * DD + k) * ld<BF>(A, k * RANK + r);
    acc += __shfl_xor(acc, 8, 64);
    acc += __shfl_xor(acc, 16, 64);
    acc += __shfl_xor(acc, 32, 64);
    if (l < 8) xa[m * RANK + l] = acc;
}
__global__ __launch_bounds__(64) void xa_kernel(const void* x, const void* A,
                                                const int* flag, float* xa) {
    if (*flag) xa_body<true>(x, A, xa);
    else       xa_body<false>(x, A, xa);
}

// -------------------------------------- qkv = x@W + b + 8*(xa@B)  (fp32 out)
// grid (6, 1024), block 256. Each thread: 4 m-rows x 2 n-cols.
template<bool BF>
__device__ void qkv_body(const void* x, const void* W, const void* bias,
                         const void* Bl, const float* __restrict__ xa,
                         float* __restrict__ qkv,
                         float (*sx)[DD], float (*sxa)[RANK]) {
    int tid = threadIdx.x;
    int m0  = blockIdx.y * 4;
    int nh  = blockIdx.x * 256 + tid;   // half-column; n = 2*nh

    for (int i = tid; i < 4 * DD; i += 256)
        sx[i >> 10][i & (DD - 1)] = ld<BF>(x, (m0 + (i >> 10)) * DD + (i & (DD - 1)));
    if (tid < 32) sxa[tid >> 3][tid & 7] = xa[m0 * RANK + tid];
    __syncthreads();

    float ax[4] = {0.f, 0.f, 0.f, 0.f};
    float ay[4] = {0.f, 0.f, 0.f, 0.f};
#pragma unroll 4
    for (int k = 0; k < DD; k++) {
        float wx = ld<BF>(W, k * N3 + 2 * nh);
        float wy = ld<BF>(W, k * N3 + 2 * nh + 1);
#pragma unroll
        for (int i = 0; i < 4; i++) {
            float xv = sx[i][k];
            ax[i] += xv * wx;
            ay[i] += xv * wy;
        }
    }
#pragma unroll
    for (int r = 0; r < RANK; r++) {
        float bx = ld<BF>(Bl, r * N3 + 2 * nh) * 8.0f;
        float by = ld<BF>(Bl, r * N3 + 2 * nh + 1) * 8.0f;
#pragma unroll
        for (int i = 0; i < 4; i++) {
            ax[i] += sxa[i][r] * bx;
            ay[i] += sxa[i][r] * by;
        }
    }
    float bxv = ld<BF>(bias, 2 * nh);
    float byv = ld<BF>(bias, 2 * nh + 1);
#pragma unroll
    for (int i = 0; i < 4; i++) {
        float2 o = make_float2(ax[i] + bxv, ay[i] + byv);
        *(float2*)&qkv[(m0 + i) * N3 + 2 * nh] = o;
    }
}
__global__ __launch_bounds__(256) void qkv_kernel(const void* x, const void* W,
                                                  const void* bias, const void* Bl,
                                                  const float* __restrict__ xa,
                                                  const int* flag,
                                                  float* __restrict__ qkv) {
    __shared__ float sx[4][DD];
    __shared__ float sxa[4][RANK];
    if (*flag) qkv_body<true>(x, W, bias, Bl, xa, qkv, sx, sxa);
    else       qkv_body<false>(x, W, bias, Bl, xa, qkv, sx, sxa);
}

// ------------------------------------------- causal attention, online softmax
// grid (S, H, B), block 64 (one wave per query row). fp32 ws in/out only.
__global__ __launch_bounds__(64) void attn_kernel(const float* __restrict__ qkv,
                                                  float* __restrict__ ctx) {
    int qi = blockIdx.x, h = blockIdx.y, b = blockIdx.z;
    int lane = threadIdx.x;
    __shared__ float sq[HDIM];
    __shared__ float sp[64];
    const float* base = qkv + (size_t)b * SS * N3;

    sq[lane] = base[qi * N3 + h * HDIM + lane];
    __syncthreads();

    float mrun = -3.0e38f, lrun = 0.f, o = 0.f;
    int nk = qi + 1;
    const float* vcol = base + 2 * DD + h * HDIM + lane;

    for (int j0 = 0; j0 < nk; j0 += 64) {
        int j = j0 + lane;
        float s = -3.0e38f;
        if (j < nk) {
            const float4* krow = (const float4*)(base + j * N3 + DD + h * HDIM);
            float acc = 0.f;
#pragma unroll
            for (int d4 = 0; d4 < HDIM / 4; d4++) {
                float4 kv = krow[d4];
                float4 qv = *(const float4*)&sq[d4 * 4];
                acc += qv.x * kv.x + qv.y * kv.y + qv.z * kv.z + qv.w * kv.w;
            }
            s = acc * 0.125f;   // (score + 0 mask)/sqrt(HD)
        }
        float cm = s;
#pragma unroll
        for (int off = 32; off >= 1; off >>= 1) cm = fmaxf(cm, __shfl_xor(cm, off, 64));
        float mn = fmaxf(mrun, cm);
        float p  = (j < nk) ? __expf(s - mn) : 0.f;
        float cs = p;
#pragma unroll
        for (int off = 32; off >= 1; off >>= 1) cs += __shfl_xor(cs, off, 64);
        float alpha = __expf(mrun - mn);

        sp[lane] = p;
        __syncthreads();

        float acc = 0.f;
        int jmax = min(64, nk - j0);
        for (int jj = 0; jj < jmax; jj++)
            acc += sp[jj] * vcol[(j0 + jj) * N3];

        o    = o * alpha + acc;
        lrun = lrun * alpha + cs;
        mrun = mn;
        __syncthreads();
    }
    ctx[((size_t)b * SS + qi) * DD + h * HDIM + lane] = o / lrun;
}

// ----------------------------------------------- out = ctx @ W_proj + b_proj
// grid (2, 1024), block 256. Each thread: 4 m-rows x 2 n-cols.
template<bool BF>
__device__ void proj_body(const float* __restrict__ ctx, const void* W,
                          const void* bias, void* out, float (*sc)[DD]) {
    int tid = threadIdx.x;
    int m0  = blockIdx.y * 4;
    int nh  = blockIdx.x * 256 + tid;   // n = 2*nh

    for (int i = tid; i < 4 * DD; i += 256)
        sc[i >> 10][i & (DD - 1)] = ctx[(m0 + (i >> 10)) * DD + (i & (DD - 1))];
    __syncthreads();

    float ax[4] = {0.f, 0.f, 0.f, 0.f};
    float ay[4] = {0.f, 0.f, 0.f, 0.f};
#pragma unroll 4
    for (int k = 0; k < DD; k++) {
        float wx = ld<BF>(W, k * DD + 2 * nh);
        float wy = ld<BF>(W, k * DD + 2 * nh + 1);
#pragma unroll
        for (int i = 0; i < 4; i++) {
            float c = sc[i][k];
            ax[i] += c * wx;
            ay[i] += c * wy;
        }
    }
    float bxv = ld<BF>(bias, 2 * nh);
    float byv = ld<BF>(bias, 2 * nh + 1);
#pragma unroll
    for (int i = 0; i < 4; i++) {
        float vx = ax[i] + bxv, vy = ay[i] + byv;
        if constexpr (BF) {
            __hip_bfloat162 o2;
            o2.x = __float2bfloat16(vx);
            o2.y = __float2bfloat16(vy);
            *(__hip_bfloat162*)&((bf16*)out)[(m0 + i) * DD + 2 * nh] = o2;
        } else {
            *(float2*)&((float*)out)[(m0 + i) * DD + 2 * nh] = make_float2(vx, vy);
        }
    }
}
__global__ __launch_bounds__(256) void proj_kernel(const float* __restrict__ ctx,
                                                   const void* W, const void* bias,
                                                   const int* flag, void* out) {
    __shared__ float sc[4][DD];
    if (*flag) proj_body<true>(ctx, W, bias, out, sc);
    else       proj_body<false>(ctx, W, bias, out, sc);
}

extern "C" void kernel_launch(void* const* d_in, const int* in_sizes, int n_in,
                              void* d_out, int out_size, void* d_ws, size_t ws_size,
                              hipStream_t stream) {
    const void* x  = d_in[0];
    const void* Wq = d_in[1];
    const void* bq = d_in[2];
    const void* Al = d_in[3];
    const void* Bl = d_in[4];
    const void* Wp = d_in[5];
    const void* bp = d_in[6];

    int*   flag = (int*)d_ws;
    float* qkv  = (float*)((char*)d_ws + 256);
    float* xa   = qkv + (size_t)MROWS * N3;    // 48 MB of qkv
    float* ctx  = xa + (size_t)MROWS * RANK;   // 128 KB of xa; ctx = 16 MB

    hipLaunchKernelGGL(sniff_kernel, dim3(1), dim3(256), 0, stream, x, flag);
    hipLaunchKernelGGL(xa_kernel, dim3(MROWS), dim3(64), 0, stream, x, Al, flag, xa);
    hipLaunchKernelGGL(qkv_kernel, dim3(N3 / 512, MROWS / 4), dim3(256), 0, stream,
                       x, Wq, bq, Bl, xa, flag, qkv);
    hipLaunchKernelGGL(attn_kernel, dim3(SS, HH, BB), dim3(64), 0, stream, qkv, ctx);
    hipLaunchKernelGGL(proj_kernel, dim3(DD / 512, MROWS / 4), dim3(256), 0, stream,
                       ctx, Wp, bp, flag, d_out);
}

// Round 7
// 2155.559 us; speedup vs baseline: 1.5991x; 1.5991x over previous
//
#include <hip/hip_runtime.h>
#include <hip/hip_bf16.h>

// B=2, S=2048, D=1024, H=16, HD=64, RANK=8, ALPHA=8
// R7 = R2 (last-known-good, passed @3446us) with ONE change: attn_kernel
// replaced by attn_flash (64-row q-tile per block, LDS K/V tiles, K cached
// in registers). R2 vocabulary only: fp32 ws, float4, __syncthreads.
// No short8 / MFMA / bf16 intermediates this round (R3-R6 all failed with
// that vocabulary; re-introduce one kernel at a time in later rounds).

#define BB    2
#define SS    2048
#define DD    1024
#define HH    16
#define HDIM  64
#define RANK  8
#define MROWS (BB * SS)   // 4096
#define N3    (3 * DD)    // 3072

typedef __hip_bfloat16 bf16;

template<bool BF>
__device__ __forceinline__ float ld(const void* p, int i) {
    if constexpr (BF) return __bfloat162float(((const bf16*)p)[i]);
    else              return ((const float*)p)[i];
}

// ------------------------------------------------------------- dtype sniffer
__global__ __launch_bounds__(256) void sniff_kernel(const void* x, int* flag) {
    __shared__ int cnt;
    if (threadIdx.x == 0) cnt = 0;
    __syncthreads();
    const unsigned short* u = (const unsigned short*)x;
    int good = 0;
    for (int i = threadIdx.x; i < 4096; i += 256) {
        unsigned short bits = u[2 * i];
        int e = (bits >> 7) & 0xFF;
        if (e >= 110 && e <= 144) good++;
    }
    atomicAdd(&cnt, good);
    __syncthreads();
    if (threadIdx.x == 0) *flag = (cnt > 3000) ? 1 : 0;
}

// ---------------------------------------------------------------- xa = x @ A
template<bool BF>
__device__ void xa_body(const void* x, const void* A, float* xa) {
    int m = blockIdx.x;
    int l = threadIdx.x;
    int r = l & 7, k0 = l >> 3;
    float acc = 0.f;
    for (int k = k0; k < DD; k += 8)
        acc += ld<BF>(x, m * DD + k) * ld<BF>(A, k * RANK + r);
    acc += __shfl_xor(acc, 8, 64);
    acc += __shfl_xor(acc, 16, 64);
    acc += __shfl_xor(acc, 32, 64);
    if (l < 8) xa[m * RANK + l] = acc;
}
__global__ __launch_bounds__(64) void xa_kernel(const void* x, const void* A,
                                                const int* flag, float* xa) {
    if (*flag) xa_body<true>(x, A, xa);
    else       xa_body<false>(x, A, xa);
}

// -------------------------------------- qkv = x@W + b + 8*(xa@B)  (fp32 out)
template<bool BF>
__device__ void qkv_body(const void* x, const void* W, const void* bias,
                         const void* Bl, const float* __restrict__ xa,
                         float* __restrict__ qkv,
                         float (*sx)[DD], float (*sxa)[RANK]) {
    int tid = threadIdx.x;
    int m0  = blockIdx.y * 4;
    int nh  = blockIdx.x * 256 + tid;   // half-column; n = 2*nh

    for (int i = tid; i < 4 * DD; i += 256)
        sx[i >> 10][i & (DD - 1)] = ld<BF>(x, (m0 + (i >> 10)) * DD + (i & (DD - 1)));
    if (tid < 32) sxa[tid >> 3][tid & 7] = xa[m0 * RANK + tid];
    __syncthreads();

    float ax[4] = {0.f, 0.f, 0.f, 0.f};
    float ay[4] = {0.f, 0.f, 0.f, 0.f};
#pragma unroll 4
    for (int k = 0; k < DD; k++) {
        float wx = ld<BF>(W, k * N3 + 2 * nh);
        float wy = ld<BF>(W, k * N3 + 2 * nh + 1);
#pragma unroll
        for (int i = 0; i < 4; i++) {
            float xv = sx[i][k];
            ax[i] += xv * wx;
            ay[i] += xv * wy;
        }
    }
#pragma unroll
    for (int r = 0; r < RANK; r++) {
        float bx = ld<BF>(Bl, r * N3 + 2 * nh) * 8.0f;
        float by = ld<BF>(Bl, r * N3 + 2 * nh + 1) * 8.0f;
#pragma unroll
        for (int i = 0; i < 4; i++) {
            ax[i] += sxa[i][r] * bx;
            ay[i] += sxa[i][r] * by;
        }
    }
    float bxv = ld<BF>(bias, 2 * nh);
    float byv = ld<BF>(bias, 2 * nh + 1);
#pragma unroll
    for (int i = 0; i < 4; i++) {
        float2 o = make_float2(ax[i] + bxv, ay[i] + byv);
        *(float2*)&qkv[(m0 + i) * N3 + 2 * nh] = o;
    }
}
__global__ __launch_bounds__(256) void qkv_kernel(const void* x, const void* W,
                                                  const void* bias, const void* Bl,
                                                  const float* __restrict__ xa,
                                                  const int* flag,
                                                  float* __restrict__ qkv) {
    __shared__ float sx[4][DD];
    __shared__ float sxa[4][RANK];
    if (*flag) qkv_body<true>(x, W, bias, Bl, xa, qkv, sx, sxa);
    else       qkv_body<false>(x, W, bias, Bl, xa, qkv, sx, sxa);
}

// --------------------------------------- flash-tile attention (fp32, no MFMA)
// grid (S/64, H, B), 256 thr = 4 waves; wave w owns q-rows qb+w*16..+15.
// Per 64-key chunk: stage K/V tiles in LDS (float4, padded rows), lane=key
// for scores (K column cached in 16 float4 regs, reused over 16 rows),
// shuffle-reduce softmax, scalar same-typed sp round-trip, lane=hd for PV.
__global__ __launch_bounds__(256) void attn_flash(const float* __restrict__ qkv,
                                                  float* __restrict__ ctx) {
    __shared__ float sq[64][68];        // [row][d], pad 68 (272 B rows, 16B-aligned)
    __shared__ float sk[64][68];        // [key][d]
    __shared__ float sv[64][68];        // [key][d]
    __shared__ float sp[4][16][64];     // [wave][row][key] (scalar-only access)

    int qt = (int)gridDim.x - 1 - (int)blockIdx.x;   // long blocks first
    int h = blockIdx.y, b = blockIdx.z;
    int tid = threadIdx.x, wav = tid >> 6, lane = tid & 63;
    int qb = qt * 64;
    const float* base = qkv + (size_t)b * SS * N3;

    // Stage Q tile once. idx: row = idx>>4, dq = idx&15 (float4 chunks).
#pragma unroll
    for (int i = 0; i < 4; i++) {
        int idx = i * 256 + tid;
        int r = idx >> 4, dq = idx & 15;
        *(float4*)&sq[r][dq * 4] =
            *(const float4*)&base[(size_t)(qb + r) * N3 + h * HDIM + dq * 4];
    }

    float o[16], m[16], l[16];
#pragma unroll
    for (int r = 0; r < 16; r++) { o[r] = 0.f; m[r] = -3.0e38f; l[r] = 0.f; }

    int nch = qt + 1;
    for (int c = 0; c < nch; ++c) {
        int k0 = c * 64;
        __syncthreads();   // protect previous chunk's sk/sv reads
#pragma unroll
        for (int i = 0; i < 4; i++) {
            int idx = i * 256 + tid;
            int r = idx >> 4, dq = idx & 15;
            size_t row = (size_t)(k0 + r) * N3 + h * HDIM + dq * 4;
            *(float4*)&sk[r][dq * 4] = *(const float4*)&base[row + DD];
            *(float4*)&sv[r][dq * 4] = *(const float4*)&base[row + 2 * DD];
        }
        __syncthreads();

        // ---- scores: lane = key (k0+lane); K column cached in registers
        float4 kreg[16];
#pragma unroll
        for (int dq = 0; dq < 16; dq++) kreg[dq] = *(float4*)&sk[lane][dq * 4];

        int key = k0 + lane;
        float al[16];
#pragma unroll
        for (int r = 0; r < 16; r++) {
            const float* qrow = &sq[wav * 16 + r][0];
            float s = 0.f;
#pragma unroll
            for (int dq = 0; dq < 16; dq++) {
                float4 qv = *(const float4*)&qrow[dq * 4];  // broadcast
                float4 kv = kreg[dq];
                s += qv.x * kv.x + qv.y * kv.y + qv.z * kv.z + qv.w * kv.w;
            }
            int q = qb + wav * 16 + r;
            bool valid = (key <= q);
            float a = valid ? s * 0.125f : -3.0e38f;
            float mx = a;
#pragma unroll
            for (int off = 32; off >= 1; off >>= 1)
                mx = fmaxf(mx, __shfl_xor(mx, off, 64));
            float mn = fmaxf(m[r], mx);
            float p = valid ? __expf(a - mn) : 0.f;
            float sm = p;
#pragma unroll
            for (int off = 32; off >= 1; off >>= 1)
                sm += __shfl_xor(sm, off, 64);
            al[r] = __expf(m[r] - mn);
            m[r] = mn;
            l[r] = l[r] * al[r] + sm;
            sp[wav][r][lane] = p;   // scalar write, scalar reads below (same type)
        }

        // ---- PV: lane = hd; V value reused across 16 rows
#pragma unroll
        for (int r = 0; r < 16; r++) o[r] *= al[r];
        for (int jj = 0; jj < 64; jj += 4) {
            float v0 = sv[jj + 0][lane];
            float v1 = sv[jj + 1][lane];
            float v2 = sv[jj + 2][lane];
            float v3 = sv[jj + 3][lane];
#pragma unroll
            for (int r = 0; r < 16; r++) {
                float p0 = sp[wav][r][jj + 0];
                float p1 = sp[wav][r][jj + 1];
                float p2 = sp[wav][r][jj + 2];
                float p3 = sp[wav][r][jj + 3];
                o[r] += p0 * v0 + p1 * v1 + p2 * v2 + p3 * v3;
            }
        }
    }

#pragma unroll
    for (int r = 0; r < 16; r++) {
        int q = qb + wav * 16 + r;
        ctx[((size_t)b * SS + q) * DD + h * HDIM + lane] = o[r] / l[r];
    }
}

// ----------------------------------------------- out = ctx @ W_proj + b_proj
template<bool BF>
__device__ void proj_body(const float* __restrict__ ctx, const void* W,
                          const void* bias, void* out, float (*sc)[DD]) {
    int tid = threadIdx.x;
    int m0  = blockIdx.y * 4;
    int nh  = blockIdx.x * 256 + tid;   // n = 2*nh

    for (int i = tid; i < 4 * DD; i += 256)
        sc[i >> 10][i & (DD - 1)] = ctx[(m0 + (i >> 10)) * DD + (i & (DD - 1))];
    __syncthreads();

    float ax[4] = {0.f, 0.f, 0.f, 0.f};
    float ay[4] = {0.f, 0.f, 0.f, 0.f};
#pragma unroll 4
    for (int k = 0; k < DD; k++) {
        float wx = ld<BF>(W, k * DD + 2 * nh);
        float wy = ld<BF>(W, k * DD + 2 * nh + 1);
#pragma unroll
        for (int i = 0; i < 4; i++) {
            float c = sc[i][k];
            ax[i] += c * wx;
            ay[i] += c * wy;
        }
    }
    float bxv = ld<BF>(bias, 2 * nh);
    float byv = ld<BF>(bias, 2 * nh + 1);
#pragma unroll
    for (int i = 0; i < 4; i++) {
        float vx = ax[i] + bxv, vy = ay[i] + byv;
        if constexpr (BF) {
            __hip_bfloat162 o2;
            o2.x = __float2bfloat16(vx);
            o2.y = __float2bfloat16(vy);
            *(__hip_bfloat162*)&((bf16*)out)[(m0 + i) * DD + 2 * nh] = o2;
        } else {
            *(float2*)&((float*)out)[(m0 + i) * DD + 2 * nh] = make_float2(vx, vy);
        }
    }
}
__global__ __launch_bounds__(256) void proj_kernel(const float* __restrict__ ctx,
                                                   const void* W, const void* bias,
                                                   const int* flag, void* out) {
    __shared__ float sc[4][DD];
    if (*flag) proj_body<true>(ctx, W, bias, out, sc);
    else       proj_body<false>(ctx, W, bias, out, sc);
}

extern "C" void kernel_launch(void* const* d_in, const int* in_sizes, int n_in,
                              void* d_out, int out_size, void* d_ws, size_t ws_size,
                              hipStream_t stream) {
    const void* x  = d_in[0];
    const void* Wq = d_in[1];
    const void* bq = d_in[2];
    const void* Al = d_in[3];
    const void* Bl = d_in[4];
    const void* Wp = d_in[5];
    const void* bp = d_in[6];

    int*   flag = (int*)d_ws;
    float* qkv  = (float*)((char*)d_ws + 256);
    float* xa   = qkv + (size_t)MROWS * N3;    // after 48 MB of qkv
    float* ctx  = xa + (size_t)MROWS * RANK;   // after 128 KB of xa; ctx = 16 MB

    hipLaunchKernelGGL(sniff_kernel, dim3(1), dim3(256), 0, stream, x, flag);
    hipLaunchKernelGGL(xa_kernel, dim3(MROWS), dim3(64), 0, stream, x, Al, flag, xa);
    hipLaunchKernelGGL(qkv_kernel, dim3(N3 / 512, MROWS / 4), dim3(256), 0, stream,
                       x, Wq, bq, Bl, xa, flag, qkv);
    hipLaunchKernelGGL(attn_flash, dim3(SS / 64, HH, BB), dim3(256), 0, stream,
                       qkv, ctx);
    hipLaunchKernelGGL(proj_kernel, dim3(DD / 512, MROWS / 4), dim3(256), 0, stream,
                       ctx, Wp, bp, flag, d_out);
}

// Round 11
// 1298.499 us; speedup vs baseline: 2.6545x; 1.6600x over previous
//
#include <hip/hip_runtime.h>
#include <hip/hip_bf16.h>

// B=2, S=2048, D=1024, H=16, HD=64, RANK=8, ALPHA=8.
// R11: ALL I/O IS FP32 (R10's 51.125 decode: bf16 stores into an fp32-decoded
// d_out show element-(2i+1) aliasing + zero tail; R2/R7 passed writing fp32).
// R11 = R10 with ONE change: mode-1 (proj) epilogue stores FP32 to d_out.
// prep: W_eff^T=(W_qkv+8*A@B)^T, W_proj^T as bf16 HI/LO pairs.
// gemm3: MFMA 16x16x32 bf16, A fp32 split hi/lo on the fly, 3 MFMAs
//        (hh+hl+lh) ~ fp32 precision. mode 0: QK fp32 + V bf16; mode 1: fp32 out.
// attn_flash: R7-proven fp32 flash tile.
// ws (60 MB): qkf 0-32 | vbb 32-40 | wpt hi 40-42 lo 42-44 |
//             wqt hi 44-50 lo 50-56 | ctxf 44-60 (overlays dead wqt).

#define BB    2
#define SS    2048
#define DD    1024
#define HH    16
#define HDIM  64
#define N3    3072
#define MR    4096

typedef short short8 __attribute__((ext_vector_type(8)));
typedef float f32x4 __attribute__((ext_vector_type(4)));

#define MFMA16(a, b, c) __builtin_amdgcn_mfma_f32_16x16x32_bf16((a), (b), (c), 0, 0, 0)

__device__ __forceinline__ float b2f(short s) {
    union { unsigned int u; float f; } c;
    c.u = ((unsigned int)(unsigned short)s) << 16;
    return c.f;
}
__device__ __forceinline__ short f2b(float f) {
    union { __hip_bfloat16 h; short s; } c;
    c.h = __float2bfloat16(f);
    return c.s;
}
struct HiLo { short hi, lo; };
__device__ __forceinline__ HiLo split2(float v) {
    HiLo r;
    r.hi = f2b(v);
    r.lo = f2b(v - b2f(r.hi));   // exact residual; next 8 mantissa bits
    return r;
}

// ---------------------------------------------------------------- prep
// Whi/Wlo[n][k] = bf16split( W[k][n] + lora*8*sum_r A[k][r]*B[r][n] ), fp32 in.
__global__ __launch_bounds__(256) void prep_kernel(
    const float* __restrict__ W, const float* __restrict__ Al,
    const float* __restrict__ Bl, short* __restrict__ Whi,
    short* __restrict__ Wlo, int N, int lora)
{
    __shared__ float sw[64][68];   // [k][n], row 272 B (16B-aligned)
    __shared__ float sa[64][8];
    __shared__ float sb[8][64];
    int tid = threadIdx.x;
    int n0 = blockIdx.x * 64, k0 = blockIdx.y * 64;
#pragma unroll
    for (int p = 0; p < 4; p++) {
        int idx = p * 256 + tid;
        int kr = idx >> 4, ch = idx & 15;
        *(f32x4*)&sw[kr][ch * 4] = *(const f32x4*)&W[(size_t)(k0 + kr) * N + n0 + ch * 4];
    }
    if (lora) {
        if (tid < 64) {
#pragma unroll
            for (int r = 0; r < 8; r++) sa[tid][r] = Al[(k0 + tid) * 8 + r];
        } else if (tid < 128) {
            int c = tid - 64;
#pragma unroll
            for (int r = 0; r < 8; r++) sb[r][c] = Bl[(size_t)r * N + n0 + c];
        }
    }
    __syncthreads();
#pragma unroll
    for (int p = 0; p < 2; p++) {
        int idx = p * 256 + tid;
        int nr = idx >> 3, ch = idx & 7;
        short8 h8, l8;
#pragma unroll
        for (int j = 0; j < 8; j++) {
            int k = ch * 8 + j;
            float v = sw[k][nr];
            if (lora) {
                float a2 = 0.f;
#pragma unroll
                for (int r = 0; r < 8; r++) a2 += sa[k][r] * sb[r][nr];
                v += 8.0f * a2;
            }
            HiLo hl = split2(v);
            h8[j] = hl.hi;
            l8[j] = hl.lo;
        }
        size_t off = (size_t)(n0 + nr) * 1024 + k0 + ch * 8;
        *(short8*)&Whi[off] = h8;
        *(short8*)&Wlo[off] = l8;
    }
}

// ---------------------------------------------------------------- gemm3
// C[m][n] = sum_k Af[m][k]*(Bhi+Blo)[n][k] + bias[n], Af fp32 split on the fly.
// K=1024, BM=BN=128, BK=32, 256 thr.
// mode 0: n<2048 -> outqk fp32 [m][2048]; n>=2048 -> outv bf16 [m][1024].
// mode 1: outf32 fp32 [m][1024]  (d_out is FP32).
__global__ __launch_bounds__(256) void gemm3(
    const float* __restrict__ Af, const short* __restrict__ Bhi,
    const short* __restrict__ Blo, const float* __restrict__ bias,
    float* __restrict__ outqk, short* __restrict__ outv,
    float* __restrict__ outf32, int N, int mode)
{
    __shared__ short Ah[4][128][8];   // [k-quad][m-row][j]
    __shared__ short Alo[4][128][8];
    __shared__ short Bh[4][128][8];   // [k-quad][n-row][j]
    __shared__ short Blo_s[4][128][8];
    int tid = threadIdx.x;
    int wav = tid >> 6, lane = tid & 63;
    int l15 = lane & 15, q4 = lane >> 4;
    int wm = wav & 1, wn = wav >> 1;
    int n0 = blockIdx.x * 128, m0 = blockIdx.y * 128;

    f32x4 acc[4][4] = {};
    int srow = tid >> 2, skq = tid & 3;

    for (int kk = 0; kk < 1024; kk += 32) {
        __syncthreads();
#pragma unroll
        for (int half = 0; half < 2; half++) {
            int row = srow + half * 64;
            const float* src = &Af[(size_t)(m0 + row) * 1024 + kk + skq * 8];
            f32x4 v0 = *(const f32x4*)src;
            f32x4 v1 = *(const f32x4*)(src + 4);
            short8 h8, l8;
#pragma unroll
            for (int j = 0; j < 4; j++) {
                HiLo hl = split2(v0[j]);
                h8[j] = hl.hi; l8[j] = hl.lo;
            }
#pragma unroll
            for (int j = 0; j < 4; j++) {
                HiLo hl = split2(v1[j]);
                h8[4 + j] = hl.hi; l8[4 + j] = hl.lo;
            }
            *(short8*)&Ah[skq][row][0]  = h8;
            *(short8*)&Alo[skq][row][0] = l8;
            size_t boff = (size_t)(n0 + row) * 1024 + kk + skq * 8;
            *(short8*)&Bh[skq][row][0]    = *(const short8*)&Bhi[boff];
            *(short8*)&Blo_s[skq][row][0] = *(const short8*)&Blo[boff];
        }
        __syncthreads();
        short8 ah[4], al[4], bh[4], bl[4];
#pragma unroll
        for (int i = 0; i < 4; i++) {
            ah[i] = *(short8*)&Ah[q4][wm * 64 + i * 16 + l15][0];
            al[i] = *(short8*)&Alo[q4][wm * 64 + i * 16 + l15][0];
            bh[i] = *(short8*)&Bh[q4][wn * 64 + i * 16 + l15][0];
            bl[i] = *(short8*)&Blo_s[q4][wn * 64 + i * 16 + l15][0];
        }
#pragma unroll
        for (int mi = 0; mi < 4; mi++)
#pragma unroll
            for (int ni = 0; ni < 4; ni++) {
                acc[mi][ni] = MFMA16(ah[mi], bh[ni], acc[mi][ni]);
                acc[mi][ni] = MFMA16(ah[mi], bl[ni], acc[mi][ni]);
                acc[mi][ni] = MFMA16(al[mi], bh[ni], acc[mi][ni]);
            }
    }
#pragma unroll
    for (int ni = 0; ni < 4; ni++) {
        int n = n0 + wn * 64 + ni * 16 + l15;
        float bv = bias[n];
#pragma unroll
        for (int mi = 0; mi < 4; mi++) {
            int mbase = m0 + wm * 64 + mi * 16 + q4 * 4;
#pragma unroll
            for (int r = 0; r < 4; r++) {
                int m = mbase + r;
                float v = acc[mi][ni][r] + bv;
                if (mode == 0) {
                    if (n < 2048) outqk[(size_t)m * 2048 + n] = v;
                    else          outv[(size_t)m * 1024 + (n - 2048)] = f2b(v);
                } else {
                    outf32[(size_t)m * 1024 + n] = v;   // R11 fix: FP32 store
                }
            }
        }
    }
}

// --------------------------------- flash-tile attention (R7-proven, fp32)
// qk fp32 [4096][2048] (Q cols 0-1023, K cols 1024-2047); V bf16 [4096][1024].
__global__ __launch_bounds__(256) void attn_flash(const float* __restrict__ qk,
                                                  const short* __restrict__ vb,
                                                  float* __restrict__ ctxf) {
    __shared__ float sq[64][68];
    __shared__ float sk[64][68];
    __shared__ float sv[64][68];
    __shared__ float sp[4][16][64];

    int qt = (int)gridDim.x - 1 - (int)blockIdx.x;   // long blocks first
    int h = blockIdx.y, b = blockIdx.z;
    int tid = threadIdx.x, wav = tid >> 6, lane = tid & 63;
    int qb = qt * 64;
    const float* bqk = qk + (size_t)b * SS * 2048;
    const short* bv  = vb + (size_t)b * SS * 1024;

#pragma unroll
    for (int i = 0; i < 4; i++) {
        int idx = i * 256 + tid;
        int r = idx >> 4, dq = idx & 15;
        *(f32x4*)&sq[r][dq * 4] =
            *(const f32x4*)&bqk[(size_t)(qb + r) * 2048 + h * HDIM + dq * 4];
    }

    float o[16], m[16], l[16];
#pragma unroll
    for (int r = 0; r < 16; r++) { o[r] = 0.f; m[r] = -3.0e38f; l[r] = 0.f; }

    int nch = qt + 1;
    for (int c = 0; c < nch; ++c) {
        int k0 = c * 64;
        __syncthreads();
#pragma unroll
        for (int i = 0; i < 4; i++) {
            int idx = i * 256 + tid;
            int r = idx >> 4, dq = idx & 15;
            *(f32x4*)&sk[r][dq * 4] =
                *(const f32x4*)&bqk[(size_t)(k0 + r) * 2048 + 1024 + h * HDIM + dq * 4];
        }
#pragma unroll
        for (int p = 0; p < 2; p++) {
            int idx = p * 256 + tid;
            int r = idx >> 3, ch = idx & 7;
            short8 v8 = *(const short8*)&bv[(size_t)(k0 + r) * 1024 + h * HDIM + ch * 8];
#pragma unroll
            for (int u = 0; u < 8; u++) sv[r][ch * 8 + u] = b2f(v8[u]);
        }
        __syncthreads();

        f32x4 kreg[16];
#pragma unroll
        for (int dq = 0; dq < 16; dq++) kreg[dq] = *(f32x4*)&sk[lane][dq * 4];

        int key = k0 + lane;
        float al[16];
#pragma unroll
        for (int r = 0; r < 16; r++) {
            const float* qrow = &sq[wav * 16 + r][0];
            float s = 0.f;
#pragma unroll
            for (int dq = 0; dq < 16; dq++) {
                f32x4 qv = *(const f32x4*)&qrow[dq * 4];
                f32x4 kv = kreg[dq];
                s += qv[0] * kv[0] + qv[1] * kv[1] + qv[2] * kv[2] + qv[3] * kv[3];
            }
            int q = qb + wav * 16 + r;
            bool valid = (key <= q);
            float a = valid ? s * 0.125f : -3.0e38f;
            float mx = a;
#pragma unroll
            for (int off = 32; off >= 1; off >>= 1)
                mx = fmaxf(mx, __shfl_xor(mx, off, 64));
            float mn = fmaxf(m[r], mx);
            float p = valid ? __expf(a - mn) : 0.f;
            float sm = p;
#pragma unroll
            for (int off = 32; off >= 1; off >>= 1)
                sm += __shfl_xor(sm, off, 64);
            al[r] = __expf(m[r] - mn);
            m[r] = mn;
            l[r] = l[r] * al[r] + sm;
            sp[wav][r][lane] = p;
        }

#pragma unroll
        for (int r = 0; r < 16; r++) o[r] *= al[r];
        for (int jj = 0; jj < 64; jj += 4) {
            float v0 = sv[jj + 0][lane];
            float v1 = sv[jj + 1][lane];
            float v2 = sv[jj + 2][lane];
            float v3 = sv[jj + 3][lane];
#pragma unroll
            for (int r = 0; r < 16; r++) {
                o[r] += sp[wav][r][jj + 0] * v0 + sp[wav][r][jj + 1] * v1 +
                        sp[wav][r][jj + 2] * v2 + sp[wav][r][jj + 3] * v3;
            }
        }
    }

#pragma unroll
    for (int r = 0; r < 16; r++) {
        int q = qb + wav * 16 + r;
        ctxf[((size_t)b * SS + q) * 1024 + h * HDIM + lane] = o[r] / l[r];
    }
}

extern "C" void kernel_launch(void* const* d_in, const int* in_sizes, int n_in,
                              void* d_out, int out_size, void* d_ws, size_t ws_size,
                              hipStream_t stream) {
    const float* x  = (const float*)d_in[0];
    const float* Wq = (const float*)d_in[1];
    const float* bq = (const float*)d_in[2];
    const float* Al = (const float*)d_in[3];
    const float* Bl = (const float*)d_in[4];
    const float* Wp = (const float*)d_in[5];
    const float* bp = (const float*)d_in[6];

    char* ws = (char*)d_ws;
    float* qkf    = (float*)(ws);                             // 0-32 MB
    short* vbb    = (short*)(ws + (size_t)32 * 1024 * 1024);  // 32-40
    short* wpt_hi = (short*)(ws + (size_t)40 * 1024 * 1024);  // 40-42
    short* wpt_lo = (short*)(ws + (size_t)42 * 1024 * 1024);  // 42-44
    short* wqt_hi = (short*)(ws + (size_t)44 * 1024 * 1024);  // 44-50
    short* wqt_lo = (short*)(ws + (size_t)50 * 1024 * 1024);  // 50-56
    float* ctxf   = (float*)(ws + (size_t)44 * 1024 * 1024);  // 44-60 (overlays wqt)

    hipLaunchKernelGGL(prep_kernel, dim3(N3 / 64, 16), dim3(256), 0, stream,
                       Wq, Al, Bl, wqt_hi, wqt_lo, N3, 1);
    hipLaunchKernelGGL(prep_kernel, dim3(DD / 64, 16), dim3(256), 0, stream,
                       Wp, (const float*)nullptr, (const float*)nullptr,
                       wpt_hi, wpt_lo, DD, 0);
    hipLaunchKernelGGL(gemm3, dim3(N3 / 128, MR / 128), dim3(256), 0, stream,
                       x, wqt_hi, wqt_lo, bq, qkf, vbb, (float*)nullptr, N3, 0);
    hipLaunchKernelGGL(attn_flash, dim3(SS / 64, HH, BB), dim3(256), 0, stream,
                       qkf, vbb, ctxf);
    hipLaunchKernelGGL(gemm3, dim3(DD / 128, MR / 128), dim3(256), 0, stream,
                       ctxf, wpt_hi, wpt_lo, bp, (float*)nullptr, (short*)nullptr,
                       (float*)d_out, DD, 1);
}

// Round 12
// 475.268 us; speedup vs baseline: 7.2525x; 2.7321x over previous
//
#include <hip/hip_runtime.h>
#include <hip/hip_bf16.h>

// B=2, S=2048, D=1024, H=16, HD=64, RANK=8, ALPHA=8. ALL I/O FP32.
// R12 = R11 (passed, 1298us, absmax 0.25) with ONE change: attn_flash ->
// attn_mfma. Scores via hi/lo-split bf16 MFMA (~fp32 precision); P,V bf16
// MFMA. prep/gemm3 byte-identical to R11 (hardware-validated).
// ws (60 MB): qkf 0-32 | vbb 32-40 | wpt hi 40-42 lo 42-44 |
//             wqt hi 44-50 lo 50-56 | ctxf 44-60 (overlays dead wqt).

#define BB    2
#define SS    2048
#define DD    1024
#define HH    16
#define HDIM  64
#define N3    3072
#define MR    4096

typedef short short8 __attribute__((ext_vector_type(8)));
typedef float f32x4 __attribute__((ext_vector_type(4)));

#define MFMA16(a, b, c) __builtin_amdgcn_mfma_f32_16x16x32_bf16((a), (b), (c), 0, 0, 0)

__device__ __forceinline__ float b2f(short s) {
    union { unsigned int u; float f; } c;
    c.u = ((unsigned int)(unsigned short)s) << 16;
    return c.f;
}
__device__ __forceinline__ short f2b(float f) {
    union { __hip_bfloat16 h; short s; } c;
    c.h = __float2bfloat16(f);
    return c.s;
}
struct HiLo { short hi, lo; };
__device__ __forceinline__ HiLo split2(float v) {
    HiLo r;
    r.hi = f2b(v);
    r.lo = f2b(v - b2f(r.hi));   // exact residual; next 8 mantissa bits
    return r;
}

// ---------------------------------------------------------------- prep
// Whi/Wlo[n][k] = bf16split( W[k][n] + lora*8*sum_r A[k][r]*B[r][n] ), fp32 in.
__global__ __launch_bounds__(256) void prep_kernel(
    const float* __restrict__ W, const float* __restrict__ Al,
    const float* __restrict__ Bl, short* __restrict__ Whi,
    short* __restrict__ Wlo, int N, int lora)
{
    __shared__ float sw[64][68];
    __shared__ float sa[64][8];
    __shared__ float sb[8][64];
    int tid = threadIdx.x;
    int n0 = blockIdx.x * 64, k0 = blockIdx.y * 64;
#pragma unroll
    for (int p = 0; p < 4; p++) {
        int idx = p * 256 + tid;
        int kr = idx >> 4, ch = idx & 15;
        *(f32x4*)&sw[kr][ch * 4] = *(const f32x4*)&W[(size_t)(k0 + kr) * N + n0 + ch * 4];
    }
    if (lora) {
        if (tid < 64) {
#pragma unroll
            for (int r = 0; r < 8; r++) sa[tid][r] = Al[(k0 + tid) * 8 + r];
        } else if (tid < 128) {
            int c = tid - 64;
#pragma unroll
            for (int r = 0; r < 8; r++) sb[r][c] = Bl[(size_t)r * N + n0 + c];
        }
    }
    __syncthreads();
#pragma unroll
    for (int p = 0; p < 2; p++) {
        int idx = p * 256 + tid;
        int nr = idx >> 3, ch = idx & 7;
        short8 h8, l8;
#pragma unroll
        for (int j = 0; j < 8; j++) {
            int k = ch * 8 + j;
            float v = sw[k][nr];
            if (lora) {
                float a2 = 0.f;
#pragma unroll
                for (int r = 0; r < 8; r++) a2 += sa[k][r] * sb[r][nr];
                v += 8.0f * a2;
            }
            HiLo hl = split2(v);
            h8[j] = hl.hi;
            l8[j] = hl.lo;
        }
        size_t off = (size_t)(n0 + nr) * 1024 + k0 + ch * 8;
        *(short8*)&Whi[off] = h8;
        *(short8*)&Wlo[off] = l8;
    }
}

// ---------------------------------------------------------------- gemm3
// C[m][n] = sum_k Af[m][k]*(Bhi+Blo)[n][k] + bias[n]; A fp32 split on the fly.
__global__ __launch_bounds__(256) void gemm3(
    const float* __restrict__ Af, const short* __restrict__ Bhi,
    const short* __restrict__ Blo, const float* __restrict__ bias,
    float* __restrict__ outqk, short* __restrict__ outv,
    float* __restrict__ outf32, int N, int mode)
{
    __shared__ short Ah[4][128][8];
    __shared__ short Alo[4][128][8];
    __shared__ short Bh[4][128][8];
    __shared__ short Blo_s[4][128][8];
    int tid = threadIdx.x;
    int wav = tid >> 6, lane = tid & 63;
    int l15 = lane & 15, q4 = lane >> 4;
    int wm = wav & 1, wn = wav >> 1;
    int n0 = blockIdx.x * 128, m0 = blockIdx.y * 128;

    f32x4 acc[4][4] = {};
    int srow = tid >> 2, skq = tid & 3;

    for (int kk = 0; kk < 1024; kk += 32) {
        __syncthreads();
#pragma unroll
        for (int half = 0; half < 2; half++) {
            int row = srow + half * 64;
            const float* src = &Af[(size_t)(m0 + row) * 1024 + kk + skq * 8];
            f32x4 v0 = *(const f32x4*)src;
            f32x4 v1 = *(const f32x4*)(src + 4);
            short8 h8, l8;
#pragma unroll
            for (int j = 0; j < 4; j++) {
                HiLo hl = split2(v0[j]);
                h8[j] = hl.hi; l8[j] = hl.lo;
            }
#pragma unroll
            for (int j = 0; j < 4; j++) {
                HiLo hl = split2(v1[j]);
                h8[4 + j] = hl.hi; l8[4 + j] = hl.lo;
            }
            *(short8*)&Ah[skq][row][0]  = h8;
            *(short8*)&Alo[skq][row][0] = l8;
            size_t boff = (size_t)(n0 + row) * 1024 + kk + skq * 8;
            *(short8*)&Bh[skq][row][0]    = *(const short8*)&Bhi[boff];
            *(short8*)&Blo_s[skq][row][0] = *(const short8*)&Blo[boff];
        }
        __syncthreads();
        short8 ah[4], al_[4], bh[4], bl[4];
#pragma unroll
        for (int i = 0; i < 4; i++) {
            ah[i]  = *(short8*)&Ah[q4][wm * 64 + i * 16 + l15][0];
            al_[i] = *(short8*)&Alo[q4][wm * 64 + i * 16 + l15][0];
            bh[i]  = *(short8*)&Bh[q4][wn * 64 + i * 16 + l15][0];
            bl[i]  = *(short8*)&Blo_s[q4][wn * 64 + i * 16 + l15][0];
        }
#pragma unroll
        for (int mi = 0; mi < 4; mi++)
#pragma unroll
            for (int ni = 0; ni < 4; ni++) {
                acc[mi][ni] = MFMA16(ah[mi], bh[ni], acc[mi][ni]);
                acc[mi][ni] = MFMA16(ah[mi], bl[ni], acc[mi][ni]);
                acc[mi][ni] = MFMA16(al_[mi], bh[ni], acc[mi][ni]);
            }
    }
#pragma unroll
    for (int ni = 0; ni < 4; ni++) {
        int n = n0 + wn * 64 + ni * 16 + l15;
        float bv = bias[n];
#pragma unroll
        for (int mi = 0; mi < 4; mi++) {
            int mbase = m0 + wm * 64 + mi * 16 + q4 * 4;
#pragma unroll
            for (int r = 0; r < 4; r++) {
                int m = mbase + r;
                float v = acc[mi][ni][r] + bv;
                if (mode == 0) {
                    if (n < 2048) outqk[(size_t)m * 2048 + n] = v;
                    else          outv[(size_t)m * 1024 + (n - 2048)] = f2b(v);
                } else {
                    outf32[(size_t)m * 1024 + n] = v;
                }
            }
        }
    }
}

// ---------------------------------------------------------------- attn_mfma
// grid (S/64, H, B), 256 thr = 4 waves x 16 q-rows. 64-key chunks.
// Scores: hi/lo bf16 MFMA (hh+hl+lh) over HD=64 (2 k-steps) -> ~fp32.
// Softmax in C-layout regs; P->bf16 A-frag via LDS; V^T via in-LDS transpose.
__global__ __launch_bounds__(256) void attn_mfma(const float* __restrict__ qk,
                                                 const short* __restrict__ vb,
                                                 float* __restrict__ ctxf) {
    __shared__ short Kh[8][64][8];      // [hd-quad][key][j]  hi
    __shared__ short Kl[8][64][8];      //                    lo
    __shared__ short Vt[8][64][8];      // [key-quad][hd][j=key-in-quad]
    __shared__ short Pt[4][8][16][8];   // [wave][key-quad][qrow][j]

    int qt = (int)gridDim.x - 1 - (int)blockIdx.x;   // long blocks first
    int h = blockIdx.y, b = blockIdx.z;
    int tid = threadIdx.x, wav = tid >> 6, lane = tid & 63;
    int l15 = lane & 15, q4 = lane >> 4;
    int qb = qt * 64;
    const float* bqk = qk + (size_t)b * SS * 2048;
    const short* bv  = vb + (size_t)b * SS * 1024;

    // Q fragments: rows qb+wav*16+l15, hd = q4*8+j (+32 for second k-step)
    size_t qoff = (size_t)(qb + wav * 16 + l15) * 2048 + h * 64;
    short8 q0h, q0l, q1h, q1l;
    {
        f32x4 a0 = *(const f32x4*)&bqk[qoff + q4 * 8];
        f32x4 a1 = *(const f32x4*)&bqk[qoff + q4 * 8 + 4];
        f32x4 c0 = *(const f32x4*)&bqk[qoff + 32 + q4 * 8];
        f32x4 c1 = *(const f32x4*)&bqk[qoff + 32 + q4 * 8 + 4];
#pragma unroll
        for (int j = 0; j < 4; j++) {
            HiLo u = split2(a0[j]); q0h[j] = u.hi; q0l[j] = u.lo;
            HiLo v = split2(a1[j]); q0h[4 + j] = v.hi; q0l[4 + j] = v.lo;
            HiLo w = split2(c0[j]); q1h[j] = w.hi; q1l[j] = w.lo;
            HiLo z = split2(c1[j]); q1h[4 + j] = z.hi; q1l[4 + j] = z.lo;
        }
    }

    f32x4 o[4] = {};
    float m[4]  = {-1e30f, -1e30f, -1e30f, -1e30f};
    float lsum[4] = {0.f, 0.f, 0.f, 0.f};

    int nch = qt + 1;
    for (int c = 0; c < nch; ++c) {
        int k0 = c * 64;
        __syncthreads();   // previous chunk's Kt/Vt reads complete
        // ---- stage K (fp32 -> hi/lo, vector LDS writes) and V^T (transpose)
#pragma unroll
        for (int p = 0; p < 2; p++) {
            int idx = p * 256 + tid;
            int key = idx >> 3, ch = idx & 7;
            const float* ks = &bqk[(size_t)(k0 + key) * 2048 + 1024 + h * 64 + ch * 8];
            f32x4 k0v = *(const f32x4*)ks;
            f32x4 k1v = *(const f32x4*)(ks + 4);
            short8 h8, l8;
#pragma unroll
            for (int j = 0; j < 4; j++) {
                HiLo u = split2(k0v[j]); h8[j] = u.hi; l8[j] = u.lo;
                HiLo v = split2(k1v[j]); h8[4 + j] = v.hi; l8[4 + j] = v.lo;
            }
            *(short8*)&Kh[ch][key][0] = h8;
            *(short8*)&Kl[ch][key][0] = l8;
            short8 v8 = *(const short8*)&bv[(size_t)(k0 + key) * 1024 + h * 64 + ch * 8];
#pragma unroll
            for (int u = 0; u < 8; u++) Vt[key >> 3][ch * 8 + u][key & 7] = v8[u];
        }
        __syncthreads();

        // ---- scores: 4 groups of 16 keys, 6 MFMAs each (hi/lo)
        f32x4 s[4];
#pragma unroll
        for (int g = 0; g < 4; g++) {
            short8 k0h_ = *(short8*)&Kh[q4][g * 16 + l15][0];
            short8 k0l_ = *(short8*)&Kl[q4][g * 16 + l15][0];
            short8 k1h_ = *(short8*)&Kh[4 + q4][g * 16 + l15][0];
            short8 k1l_ = *(short8*)&Kl[4 + q4][g * 16 + l15][0];
            f32x4 acc = {};
            acc = MFMA16(q0h, k0h_, acc);
            acc = MFMA16(q0h, k0l_, acc);
            acc = MFMA16(q0l, k0h_, acc);
            acc = MFMA16(q1h, k1h_, acc);
            acc = MFMA16(q1h, k1l_, acc);
            acc = MFMA16(q1l, k1h_, acc);
            s[g] = acc;
        }

        // ---- online softmax per row r (C layout: col=l15 key, row=q4*4+r)
        float alpha[4];
#pragma unroll
        for (int r = 0; r < 4; r++) {
            int q = qb + wav * 16 + q4 * 4 + r;
            float a[4];
#pragma unroll
            for (int g = 0; g < 4; g++) {
                int key = k0 + g * 16 + l15;
                a[g] = (key <= q) ? s[g][r] * 0.125f : -1e30f;
            }
            float mx = fmaxf(fmaxf(a[0], a[1]), fmaxf(a[2], a[3]));
            mx = fmaxf(mx, __shfl_xor(mx, 1, 64));
            mx = fmaxf(mx, __shfl_xor(mx, 2, 64));
            mx = fmaxf(mx, __shfl_xor(mx, 4, 64));
            mx = fmaxf(mx, __shfl_xor(mx, 8, 64));
            float mn = fmaxf(m[r], mx);
            float p0 = __expf(a[0] - mn), p1 = __expf(a[1] - mn);
            float p2 = __expf(a[2] - mn), p3 = __expf(a[3] - mn);
            float sm = p0 + p1 + p2 + p3;
            sm += __shfl_xor(sm, 1, 64);
            sm += __shfl_xor(sm, 2, 64);
            sm += __shfl_xor(sm, 4, 64);
            sm += __shfl_xor(sm, 8, 64);
            alpha[r] = __expf(m[r] - mn);
            m[r] = mn;
            lsum[r] = lsum[r] * alpha[r] + sm;
            int kq = (l15 >> 3), j = l15 & 7, row = q4 * 4 + r;
            Pt[wav][0 + kq][row][j] = f2b(p0);
            Pt[wav][2 + kq][row][j] = f2b(p1);
            Pt[wav][4 + kq][row][j] = f2b(p2);
            Pt[wav][6 + kq][row][j] = f2b(p3);
        }
        __syncthreads();   // Pt/Vt scalar writes visible before vector reads

        // ---- PV: A = P (keys 0..31 / 32..63), B = V^T
        short8 pf0 = *(short8*)&Pt[wav][q4][l15][0];
        short8 pf1 = *(short8*)&Pt[wav][4 + q4][l15][0];
#pragma unroll
        for (int gg = 0; gg < 4; gg++) {
            short8 vf0 = *(short8*)&Vt[q4][gg * 16 + l15][0];
            short8 vf1 = *(short8*)&Vt[4 + q4][gg * 16 + l15][0];
            f32x4 t = o[gg];
            t[0] *= alpha[0]; t[1] *= alpha[1]; t[2] *= alpha[2]; t[3] *= alpha[3];
            t = MFMA16(pf0, vf0, t);
            t = MFMA16(pf1, vf1, t);
            o[gg] = t;
        }
    }

#pragma unroll
    for (int gg = 0; gg < 4; gg++)
#pragma unroll
        for (int r = 0; r < 4; r++) {
            int q = qb + wav * 16 + q4 * 4 + r;
            ctxf[((size_t)b * SS + q) * 1024 + h * 64 + gg * 16 + l15] =
                o[gg][r] / lsum[r];
        }
}

extern "C" void kernel_launch(void* const* d_in, const int* in_sizes, int n_in,
                              void* d_out, int out_size, void* d_ws, size_t ws_size,
                              hipStream_t stream) {
    const float* x  = (const float*)d_in[0];
    const float* Wq = (const float*)d_in[1];
    const float* bq = (const float*)d_in[2];
    const float* Al = (const float*)d_in[3];
    const float* Bl = (const float*)d_in[4];
    const float* Wp = (const float*)d_in[5];
    const float* bp = (const float*)d_in[6];

    char* ws = (char*)d_ws;
    float* qkf    = (float*)(ws);                             // 0-32 MB
    short* vbb    = (short*)(ws + (size_t)32 * 1024 * 1024);  // 32-40
    short* wpt_hi = (short*)(ws + (size_t)40 * 1024 * 1024);  // 40-42
    short* wpt_lo = (short*)(ws + (size_t)42 * 1024 * 1024);  // 42-44
    short* wqt_hi = (short*)(ws + (size_t)44 * 1024 * 1024);  // 44-50
    short* wqt_lo = (short*)(ws + (size_t)50 * 1024 * 1024);  // 50-56
    float* ctxf   = (float*)(ws + (size_t)44 * 1024 * 1024);  // 44-60 (overlays wqt)

    hipLaunchKernelGGL(prep_kernel, dim3(N3 / 64, 16), dim3(256), 0, stream,
                       Wq, Al, Bl, wqt_hi, wqt_lo, N3, 1);
    hipLaunchKernelGGL(prep_kernel, dim3(DD / 64, 16), dim3(256), 0, stream,
                       Wp, (const float*)nullptr, (const float*)nullptr,
                       wpt_hi, wpt_lo, DD, 0);
    hipLaunchKernelGGL(gemm3, dim3(N3 / 128, MR / 128), dim3(256), 0, stream,
                       x, wqt_hi, wqt_lo, bq, qkf, vbb, (float*)nullptr, N3, 0);
    hipLaunchKernelGGL(attn_mfma, dim3(SS / 64, HH, BB), dim3(256), 0, stream,
                       qkf, vbb, ctxf);
    hipLaunchKernelGGL(gemm3, dim3(DD / 128, MR / 128), dim3(256), 0, stream,
                       ctxf, wpt_hi, wpt_lo, bp, (float*)nullptr, (short*)nullptr,
                       (float*)d_out, DD, 1);
}